// Round 3
// baseline (79.412 us; speedup 1.0000x reference)
//
#include <hip/hip_runtime.h>

// RelativeAttentionPositions: out[b,h,s,t] = dot(tensor[b,h,s,:], E[clip(t-s,-128,128)+128,:]) + bias[h]
// B=4 H=16 S=1024 D=64 MAX_REL=128 VOCAB=257.
// v3: per-wave independent (no barrier). Wave computes c for its own 16 rows via MFMA,
// then expands using the band structure: [0,s-128) = c0 const, 257-window varying,
// (s+128,1023] = c256 const. Constants + window stored as float4 (window LDS reads made
// 8B-aligned via per-row pad = s&3). Store-instruction count per row: ~6 vs 16 scalar.

constexpr int S_   = 1024;
constexpr int D_   = 64;
constexpr int BQ   = 64;    // rows per block = 4 waves x 16
constexpr int CPAD = 264;   // u16 stride per local row (257 + pad<=3 + slack)

typedef __attribute__((ext_vector_type(8))) short short8;   // 8 bf16 (MFMA A/B frag)
typedef __attribute__((ext_vector_type(4))) float f32x4;    // MFMA C/D frag

__device__ __forceinline__ unsigned short f2bf(float x) {
  unsigned u = __float_as_uint(x);
  return (unsigned short)((u + 0x7fffu + ((u >> 16) & 1u)) >> 16);  // RNE
}
__device__ __forceinline__ float bfu2f(unsigned short h) {
  return __uint_as_float(((unsigned)h) << 16);
}
__device__ __forceinline__ short8 pack8(float4 a, float4 b) {
  short8 r;
  r[0] = (short)f2bf(a.x); r[1] = (short)f2bf(a.y);
  r[2] = (short)f2bf(a.z); r[3] = (short)f2bf(a.w);
  r[4] = (short)f2bf(b.x); r[5] = (short)f2bf(b.y);
  r[6] = (short)f2bf(b.z); r[7] = (short)f2bf(b.w);
  return r;
}

__global__ __launch_bounds__(256, 4)
void relpos_v3(const float* __restrict__ tensor,
               const float* __restrict__ relk,
               const float* __restrict__ bias,
               float* __restrict__ out) {
  __shared__ __align__(16) unsigned short c_lds[4 * 16 * CPAD];  // 33792 B

  const int tid  = threadIdx.x;
  const int lane = tid & 63;
  const int w    = tid >> 6;          // wave id; wave owns rows s0+16w .. s0+16w+15
  const int bh   = blockIdx.x >> 4;
  const int s0   = (blockIdx.x & 15) * BQ;
  const int h    = bh & 15;
  const int l15  = lane & 15;
  const int l4   = lane >> 4;

  unsigned short* cw = c_lds + w * 16 * CPAD;   // this wave's slab: [16 rows][CPAD]

  // ---- A fragments: rows s0+16w+l15, k = l4*8 (+0 / +32) ----
  const float* xrow = tensor + ((size_t)(bh * S_ + s0 + 16 * w + l15)) * D_ + l4 * 8;
  short8 a0 = pack8(*reinterpret_cast<const float4*>(xrow),
                    *reinterpret_cast<const float4*>(xrow + 4));
  short8 a1 = pack8(*reinterpret_cast<const float4*>(xrow + 32),
                    *reinterpret_cast<const float4*>(xrow + 36));
  const float bv = bias[h];

  // ---- compute c[r][v] = dot(x[r], E[v]) + bias, bf16, row-padded by (row&3) ----
  for (int nt = 0; nt < 17; ++nt) {
    const int vcol = 16 * nt + l15;
    const int erow = vcol > 256 ? 256 : vcol;
    const float* ep = relk + (size_t)erow * D_ + l4 * 8;
    short8 b0 = pack8(*reinterpret_cast<const float4*>(ep),
                      *reinterpret_cast<const float4*>(ep + 4));
    short8 b1 = pack8(*reinterpret_cast<const float4*>(ep + 32),
                      *reinterpret_cast<const float4*>(ep + 36));
    f32x4 acc = {0.f, 0.f, 0.f, 0.f};
    acc = __builtin_amdgcn_mfma_f32_16x16x32_bf16(a0, b0, acc, 0, 0, 0);
    acc = __builtin_amdgcn_mfma_f32_16x16x32_bf16(a1, b1, acc, 0, 0, 0);
    // D mapping [m89]: col = l15 (= v), row = l4*4 + i
    if (vcol <= 256) {
      const int r0 = l4 * 4;
#pragma unroll
      for (int i = 0; i < 4; ++i) {
        // local row rloc = r0+i; global s = s0+16w+rloc; pad = s&3 = i (s0,16w are mult of 4)
        cw[(r0 + i) * CPAD + i + vcol] = f2bf(acc[i] + bv);
      }
    }
  }
  // No barrier: same-wave ds_write -> ds_read, compiler orders via lgkmcnt.

  // ---- expand the wave's 16 rows ----
#pragma unroll 4
  for (int rl = 0; rl < 16; ++rl) {
    const int s   = s0 + 16 * w + rl;
    const int pad = rl & 3;                       // = s & 3
    const unsigned short* cr = cw + rl * CPAD;
    float* orow = out + ((size_t)bh * S_ + s) * (size_t)S_;

    const float c0f   = bfu2f(cr[pad]);           // broadcast reads
    const float c256f = bfu2f(cr[pad + 256]);
    const float4 c0v   = make_float4(c0f, c0f, c0f, c0f);
    const float4 c256v = make_float4(c256f, c256f, c256f, c256f);

    const int w0  = s - 128 < 0 ? 0 : s - 128;    // varying window [w0, w1)
    const int w1  = s + 129 > S_ ? S_ : s + 129;
    const int La  = w0 & ~3;                      // left-const x4 region [0, La)
    const int w0a = (w0 + 3) & ~3;                // interior x4 region [w0a, w1a)
    const int w1a = w1 & ~3;
    const int Ra  = (w1 + 3) & ~3;                // right-const x4 region [Ra, S_)

    // left constant (v = 0)
    const int nL = La >> 2;
    for (int j = 0; 64 * j < nL; ++j) {
      int slot = lane + 64 * j;
      if (slot < nL)
        *reinterpret_cast<float4*>(&orow[4 * slot]) = c0v;
    }
    // right constant (v = 256)
    const int nR = (S_ - Ra) >> 2;
    for (int j = 0; 64 * j < nR; ++j) {
      int slot = lane + 64 * j;
      if (slot < nR)
        *reinterpret_cast<float4*>(&orow[Ra + 4 * slot]) = c256v;
    }
    // interior varying window: aligned float4 stores, aligned ds_read_b64 gathers
    const int n4 = (w1a - w0a) >> 2;              // 31..65
    for (int j = 0; j < 2; ++j) {
      int slot = lane + 64 * j;
      if (slot < n4) {
        int t0 = w0a + 4 * slot;
        int vI = t0 - s + 128 + pad;              // multiple of 4 -> 8B-aligned
        uint2 q = *reinterpret_cast<const uint2*>(&cr[vI]);
        float4 o;
        o.x = __uint_as_float(q.x << 16);
        o.y = __uint_as_float(q.x & 0xffff0000u);
        o.z = __uint_as_float(q.y << 16);
        o.w = __uint_as_float(q.y & 0xffff0000u);
        *reinterpret_cast<float4*>(&orow[t0]) = o;
      }
    }
    // edge slivers (<=4 elems each side when window ends unaligned)
    if (lane < 8) {
      const bool left  = (w0 & 3) != 0;
      const bool right = (w1 & 3) != 0;
      const bool act   = (lane < 4) ? left : right;
      if (act) {
        int t = (lane < 4) ? (La + lane) : (w1a + (lane - 4));
        int v = t - s + 128;
        v = v < 0 ? 0 : (v > 256 ? 256 : v);
        orow[t] = bfu2f(cr[pad + v]);
      }
    }
  }
}

extern "C" void kernel_launch(void* const* d_in, const int* in_sizes, int n_in,
                              void* d_out, int out_size, void* d_ws, size_t ws_size,
                              hipStream_t stream) {
  const float* tensor = (const float*)d_in[0];
  const float* relk   = (const float*)d_in[1];
  // d_in[2] = rel_values_emb (unused in forward), d_in[4] = max_relative_position (=128)
  const float* bias   = (const float*)d_in[3];
  float* out          = (float*)d_out;

  const int B = 4, H = 16;
  dim3 grid(B * H * (S_ / BQ));   // 1024 blocks, 4/CU
  dim3 block(256);
  relpos_v3<<<grid, block, 0, stream>>>(tensor, relk, bias, out);
}

// Round 4
// 73.664 us; speedup vs baseline: 1.0780x; 1.0780x over previous
//
#include <hip/hip_runtime.h>

// RelativeAttentionPositions: out[b,h,s,t] = dot(tensor[b,h,s,:], E[clip(t-s,-128,128)+128,:]) + bias[h]
// B=4 H=16 S=1024 D=64 MAX_REL=128 VOCAB=257.
// v4: MFMA computes c-rows into a margin-replicated LDS table; expand is a single
// branchless memset-shaped sweep: per block, contiguous 256KB written with float4
// stores in flat order (fill-kernel-like stream), one aligned ds_read_b64 per float4.
//
// c-row layout (u16 bf16, pitch CPITCH=276): R[0..pad+3]=c0 margin, R[pad+4+v]=c[v]
// (v=0..256), R[pad+261..267]=c256 margin, pad=s&3. Then for t0=4k:
//   m0 = pad+4+t0+128-s  is ALWAYS ==0 mod 4 (alignment-proof: pad-s+t0 ≡ 0),
//   clamp(m0,0,264) lands on replicated-c0 (R[0..3]) / replicated-c256 (R[264..267]).

constexpr int S_     = 1024;
constexpr int D_     = 64;
constexpr int BQ     = 64;    // rows per block = 4 waves x 16
constexpr int CPITCH = 276;   // u16 pitch: 552B ≡ 0 mod 8 (aligned b64), 138 dwords ≡ 10 mod 32

typedef __attribute__((ext_vector_type(8))) short short8;   // 8 bf16 (MFMA A/B frag)
typedef __attribute__((ext_vector_type(4))) float f32x4;    // MFMA C/D frag

__device__ __forceinline__ unsigned short f2bf(float x) {
  unsigned u = __float_as_uint(x);
  return (unsigned short)((u + 0x7fffu + ((u >> 16) & 1u)) >> 16);  // RNE
}
__device__ __forceinline__ short8 pack8(float4 a, float4 b) {
  short8 r;
  r[0] = (short)f2bf(a.x); r[1] = (short)f2bf(a.y);
  r[2] = (short)f2bf(a.z); r[3] = (short)f2bf(a.w);
  r[4] = (short)f2bf(b.x); r[5] = (short)f2bf(b.y);
  r[6] = (short)f2bf(b.z); r[7] = (short)f2bf(b.w);
  return r;
}

__global__ __launch_bounds__(256, 4)
void relpos_v4(const float* __restrict__ tensor,
               const float* __restrict__ relk,
               const float* __restrict__ bias,
               float* __restrict__ out) {
  __shared__ __align__(16) unsigned short c_lds[BQ * CPITCH];  // 35328 B -> 4 blocks/CU

  const int tid  = threadIdx.x;
  const int lane = tid & 63;
  const int w    = tid >> 6;          // wave id; wave computes rows 16w..16w+15
  const int bh   = blockIdx.x >> 4;
  const int s0   = (blockIdx.x & 15) * BQ;
  const int h    = bh & 15;
  const int l15  = lane & 15;
  const int l4   = lane >> 4;
  const int r0   = 16 * w + l4 * 4;   // first of the 4 block-local rows this lane holds

  // ---- A fragments: rows s0+16w+l15, k = l4*8 (+0 / +32) ----
  const float* xrow = tensor + ((size_t)(bh * S_ + s0 + 16 * w + l15)) * D_ + l4 * 8;
  short8 a0 = pack8(*reinterpret_cast<const float4*>(xrow),
                    *reinterpret_cast<const float4*>(xrow + 4));
  short8 a1 = pack8(*reinterpret_cast<const float4*>(xrow + 32),
                    *reinterpret_cast<const float4*>(xrow + 36));
  const float bv = bias[h];

  // ---- compute c-table with margins ----
#pragma unroll 2
  for (int nt = 0; nt < 17; ++nt) {
    const int vcol = 16 * nt + l15;
    const int erow = vcol > 256 ? 256 : vcol;
    const float* ep = relk + (size_t)erow * D_ + l4 * 8;
    short8 b0 = pack8(*reinterpret_cast<const float4*>(ep),
                      *reinterpret_cast<const float4*>(ep + 4));
    short8 b1 = pack8(*reinterpret_cast<const float4*>(ep + 32),
                      *reinterpret_cast<const float4*>(ep + 36));
    f32x4 acc = {0.f, 0.f, 0.f, 0.f};
    acc = __builtin_amdgcn_mfma_f32_16x16x32_bf16(a0, b0, acc, 0, 0, 0);
    acc = __builtin_amdgcn_mfma_f32_16x16x32_bf16(a1, b1, acc, 0, 0, 0);
    // D mapping [m89]: col = l15 (= v-16nt), row = l4*4 + i
    if (vcol <= 256) {
#pragma unroll
      for (int i = 0; i < 4; ++i) {
        // block-local row rl = r0+i; pad = (s&3) = i since s0, r0 are multiples of 4
        c_lds[(r0 + i) * CPITCH + i + 4 + vcol] = f2bf(acc[i] + bv);
      }
    }
    if (l15 == 0 && nt == 0) {        // these lanes hold c[row][0] -> left margins
#pragma unroll
      for (int i = 0; i < 4; ++i) {
        const unsigned short cv = f2bf(acc[i] + bv);
        for (int j = 0; j <= i + 3; ++j) c_lds[(r0 + i) * CPITCH + j] = cv;
      }
    }
    if (l15 == 0 && nt == 16) {       // these lanes hold c[row][256] -> right margins
#pragma unroll
      for (int i = 0; i < 4; ++i) {
        const unsigned short cv = f2bf(acc[i] + bv);
        for (int j = i + 261; j < 268; ++j) c_lds[(r0 + i) * CPITCH + j] = cv;
      }
    }
  }
  __syncthreads();

  // ---- expand: flat memset-shaped sweep of the block's contiguous 256 KB ----
  float* obase = out + ((size_t)bh * S_ + s0) * (size_t)S_;
  const int mc = 132 - s0;            // m0 = t0 + (rl&3) + 132 - s0 - rl
#pragma unroll 4
  for (int it = 0; it < 64; ++it) {
    const int idx = it * 256 + tid;   // float4 index within block region (0..16383)
    const int rl  = idx >> 8;         // block-local row 0..63
    const int t0  = (idx & 255) << 2;
    int m0 = t0 + (rl & 3) + mc - rl;
    m0 = m0 < 0 ? 0 : (m0 > 264 ? 264 : m0);
    const uint2 q = *reinterpret_cast<const uint2*>(&c_lds[rl * CPITCH + m0]);
    float4 o;
    o.x = __uint_as_float(q.x << 16);
    o.y = __uint_as_float(q.x & 0xffff0000u);
    o.z = __uint_as_float(q.y << 16);
    o.w = __uint_as_float(q.y & 0xffff0000u);
    *reinterpret_cast<float4*>(&obase[(size_t)idx * 4]) = o;
  }
}

extern "C" void kernel_launch(void* const* d_in, const int* in_sizes, int n_in,
                              void* d_out, int out_size, void* d_ws, size_t ws_size,
                              hipStream_t stream) {
  const float* tensor = (const float*)d_in[0];
  const float* relk   = (const float*)d_in[1];
  // d_in[2] = rel_values_emb (unused in forward), d_in[4] = max_relative_position (=128)
  const float* bias   = (const float*)d_in[3];
  float* out          = (float*)d_out;

  const int B = 4, H = 16;
  dim3 grid(B * H * (S_ / BQ));   // 1024 blocks, 4/CU, fully resident
  dim3 block(256);
  relpos_v4<<<grid, block, 0, stream>>>(tensor, relk, bias, out);
}